// Round 3
// baseline (681.011 us; speedup 1.0000x reference)
//
#include <hip/hip_runtime.h>

#define BATCH 8
#define NCLS 80
#define APIX 21504   // anchors per image: 16384 + 4096 + 1024
#define AL0 16384
#define AL1 20480
#define NSEL 3000
#define TOPK 100
#define NBINS 32768
#define BNDCAP 4096

__device__ __forceinline__ unsigned f2s(float f){
  unsigned u = __float_as_uint(f);
  return (u & 0x80000000u) ? ~u : (u | 0x80000000u);
}
__device__ __forceinline__ float s2f(unsigned u){
  return (u & 0x80000000u) ? __uint_as_float(u ^ 0x80000000u) : __uint_as_float(~u);
}
__device__ __forceinline__ float sigd(float x){
  return (float)(1.0 / (1.0 + exp(-(double)x)));
}
__device__ __forceinline__ float expd(float x){
  return (float)exp((double)x);     // correctly-rounded fp32 exp (matches libm-class expf)
}

// ---------------- decode: maxlogit key + DFL box, histogram for radix-select --------
__global__ __launch_bounds__(256) void k_decode(
    const float* __restrict__ cls0, const float* __restrict__ cls1, const float* __restrict__ cls2,
    const float* __restrict__ bp0,  const float* __restrict__ bp1,  const float* __restrict__ bp2,
    unsigned* __restrict__ keys, float4* __restrict__ boxes, unsigned* __restrict__ hist){
  int gid = blockIdx.x*256 + threadIdx.x;
  if (gid >= BATCH*APIX) return;
  int b = gid / APIX, a = gid - b*APIX;
  const float *cls, *bp; int loc, W; float stride; int l;
  if (a < AL0){ l=0; loc=a;      W=128; stride=8.f;  cls=cls0 + (size_t)b*16384*80; bp=bp0 + (size_t)b*16384*32; }
  else if (a < AL1){ l=1; loc=a-AL0; W=64; stride=16.f; cls=cls1 + (size_t)b*4096*80; bp=bp1 + (size_t)b*4096*32; }
  else { l=2; loc=a-AL1; W=32; stride=32.f; cls=cls2 + (size_t)b*1024*80; bp=bp2 + (size_t)b*1024*32; }
  const float4* c4 = (const float4*)(cls + (size_t)loc*80);
  float m = -3.4e38f;
  #pragma unroll
  for (int i=0;i<20;i++){ float4 v = c4[i]; m = fmaxf(m, fmaxf(fmaxf(v.x,v.y), fmaxf(v.z,v.w))); }
  unsigned key = f2s(m);
  keys[gid] = key;
  atomicAdd(&hist[((b*3+l)<<15) + (key>>17)], 1u);

  const float4* p4 = (const float4*)(bp + (size_t)loc*32);
  float d[4];
  #pragma unroll
  for (int g=0; g<4; g++){
    float4 lo = p4[2*g], hi = p4[2*g+1];
    float mm = fmaxf(fmaxf(fmaxf(lo.x,lo.y),fmaxf(lo.z,lo.w)), fmaxf(fmaxf(hi.x,hi.y),fmaxf(hi.z,hi.w)));
    float e0=expd(lo.x-mm), e1=expd(lo.y-mm), e2=expd(lo.z-mm), e3=expd(lo.w-mm);
    float e4=expd(hi.x-mm), e5=expd(hi.y-mm), e6=expd(hi.z-mm), e7=expd(hi.w-mm);
    float s = e0+e1+e2+e3+e4+e5+e6+e7;
    // ref: softmax (per-element divide) then dot with [0..7]
    float dot = (e1/s) + 2.f*(e2/s) + 3.f*(e3/s) + 4.f*(e4/s) + 5.f*(e5/s) + 6.f*(e6/s) + 7.f*(e7/s);
    d[g] = dot * stride;   // stride is a power of two: exact scaling, matches ref
  }
  float py = ((float)(loc / W) + 0.5f) * stride;
  float px = ((float)(loc % W) + 0.5f) * stride;
  float y1v = fminf(fmaxf(py - d[0], 0.f), 1024.f);
  float x1v = fminf(fmaxf(px - d[1], 0.f), 1024.f);
  float y2v = fminf(fmaxf(py + d[2], 0.f), 1024.f);
  float x2v = fminf(fmaxf(px + d[3], 0.f), 1024.f);
  boxes[gid] = make_float4(x1v, y1v, x2v, y2v);
}

// ---------------- find top-1000 threshold bin per (image, level) --------------------
__global__ __launch_bounds__(256) void k_thresh(const unsigned* __restrict__ hist,
                                                unsigned* __restrict__ thr){
  int bl = blockIdx.x;
  const unsigned* h = hist + ((size_t)bl << 15);
  __shared__ unsigned part[256];
  int t = threadIdx.x;
  unsigned sum = 0; int base = t*128;
  for (int i=0;i<128;i++) sum += h[base+i];
  part[t] = sum;
  __syncthreads();
  for (int off=1; off<256; off<<=1){              // inclusive suffix sum over chunks
    unsigned v = part[t];
    unsigned add = (t+off < 256) ? part[t+off] : 0u;
    __syncthreads();
    part[t] = v + add;
    __syncthreads();
  }
  unsigned sfx = part[t];
  unsigned nxt = (t==255) ? 0u : part[t+1];
  if (sfx >= 1000u && nxt < 1000u){               // crossing chunk: exactly one thread
    unsigned c = nxt;
    for (int u=127; u>=0; u--){
      unsigned hv = h[base+u];
      c += hv;
      if (c >= 1000u){
        thr[bl*4+0] = (unsigned)(base+u);          // T
        thr[bl*4+1] = c - hv;                      // count strictly above T
        thr[bl*4+2] = 1000u - (c - hv);            // r from boundary bin
        break;
      }
    }
  }
}

// ---------------- compaction: sure selections + boundary-bin list -------------------
__global__ __launch_bounds__(256) void k_select(const unsigned* __restrict__ keys,
    const unsigned* __restrict__ thr, unsigned* __restrict__ sel_cnt,
    unsigned* __restrict__ sel_idx, unsigned long long* __restrict__ bnd,
    unsigned* __restrict__ bnd_cnt){
  int gid = blockIdx.x*256 + threadIdx.x;
  if (gid >= BATCH*APIX) return;
  int b = gid / APIX, a = gid - b*APIX;
  int l = (a < AL0) ? 0 : (a < AL1 ? 1 : 2);
  unsigned key = keys[gid];
  int bl = b*3 + l;
  unsigned T = thr[bl*4];
  unsigned bin = key >> 17;
  if (bin > T){
    unsigned p = atomicAdd(&sel_cnt[bl], 1u);
    sel_idx[b*NSEL + l*1000 + p] = (unsigned)a;
  } else if (bin == T){
    unsigned q = atomicAdd(&bnd_cnt[bl], 1u);
    if (q < BNDCAP) bnd[(size_t)bl*BNDCAP + q] = ((unsigned long long)key << 32) | (0xFFFFFFFFu - (unsigned)a);
  }
}

// ---------------- exact rank within boundary bin ------------------------------------
__global__ __launch_bounds__(256) void k_bnd(const unsigned long long* __restrict__ bnd,
    const unsigned* __restrict__ bnd_cnt, const unsigned* __restrict__ thr,
    unsigned* __restrict__ sel_cnt, unsigned* __restrict__ sel_idx){
  int bl = blockIdx.x; int b = bl/3, l = bl%3;
  __shared__ unsigned long long sb[BNDCAP];
  unsigned Q = bnd_cnt[bl]; if (Q > (unsigned)BNDCAP) Q = BNDCAP;
  unsigned r = thr[bl*4 + 2];
  for (unsigned i=threadIdx.x; i<Q; i+=256) sb[i] = bnd[(size_t)bl*BNDCAP + i];
  __syncthreads();
  for (unsigned i=threadIdx.x; i<Q; i+=256){
    unsigned long long me = sb[i];
    unsigned rank = 0;
    for (unsigned j=0; j<Q; j++) rank += (sb[j] > me) ? 1u : 0u;
    if (rank < r){
      unsigned p = atomicAdd(&sel_cnt[bl], 1u);
      sel_idx[b*NSEL + l*1000 + p] = 0xFFFFFFFFu - (unsigned)(me & 0xFFFFFFFFull);
    }
  }
}

// ---------------- sort each level's 1000 by (maxlogit desc, idx asc) — match top_k order
__global__ __launch_bounds__(512) void k_sortsel(const unsigned* __restrict__ keys,
                                                 unsigned* __restrict__ sel_idx){
  int bl = blockIdx.x; int b = bl/3, l = bl%3;
  __shared__ unsigned long long s[1024];
  unsigned* base = sel_idx + b*NSEL + l*1000;
  int t = threadIdx.x;
  for (int i=t; i<1024; i+=512){
    unsigned long long v = 0ull;                  // padding: strictly smallest
    if (i < 1000){
      unsigned a = base[i];
      v = ((unsigned long long)keys[(size_t)b*APIX + a] << 32) | (0xFFFFFFFFu - a);
    }
    s[i] = v;
  }
  __syncthreads();
  for (int k=2; k<=1024; k<<=1){
    for (int j=k>>1; j>0; j>>=1){
      for (int i=t; i<1024; i+=512){
        int ixj = i ^ j;
        if (ixj > i){
          bool up = ((i & k) == 0);
          unsigned long long x = s[i], y = s[ixj];
          bool sw = up ? (x < y) : (x > y);       // descending sort
          if (sw){ s[i] = y; s[ixj] = x; }
        }
      }
      __syncthreads();
    }
  }
  for (int i=t; i<1000; i+=512) base[i] = 0xFFFFFFFFu - (unsigned)(s[i] & 0xFFFFFFFFull);
}

// ---------------- gather per-class scores (transposed) + selected boxes -------------
__global__ __launch_bounds__(256) void k_gather(
    const float* __restrict__ cls0, const float* __restrict__ cls1, const float* __restrict__ cls2,
    const unsigned* __restrict__ sel_idx, const float4* __restrict__ boxes_dec,
    float* __restrict__ scores_t, float4* __restrict__ sel_boxes){
  int b = blockIdx.x / 47, tile = blockIdx.x % 47;
  int slot_base = tile*64;
  __shared__ float tilebuf[64][84];
  __shared__ unsigned sanchor[64];
  int t = threadIdx.x, sl = t & 63, cg = t >> 6;
  int slot = slot_base + sl;
  bool valid = slot < NSEL;
  if (t < 64){
    int s2 = slot_base + t;
    sanchor[t] = (s2 < NSEL) ? sel_idx[b*NSEL + s2] : 0u;
  }
  __syncthreads();
  unsigned a = sanchor[sl];
  const float* crow;
  if (a < AL0)      crow = cls0 + ((size_t)b*16384 + a)*80;
  else if (a < AL1) crow = cls1 + ((size_t)b*4096 + (a-AL0))*80;
  else              crow = cls2 + ((size_t)b*1024 + (a-AL1))*80;
  const float4* c4 = (const float4*)crow + cg*5;
  float4 v0=c4[0], v1=c4[1], v2=c4[2], v3=c4[3], v4=c4[4];
  float4* drow = (float4*)&tilebuf[sl][cg*20];
  drow[0]=v0; drow[1]=v1; drow[2]=v2; drow[3]=v3; drow[4]=v4;
  __syncthreads();
  #pragma unroll
  for (int it=0; it<20; it++){
    int cc = it*4 + cg;
    if (valid) scores_t[((size_t)b*NCLS + cc)*NSEL + slot] = sigd(tilebuf[sl][cc]);
  }
  if (t < 64 && slot_base + t < NSEL){
    unsigned aa = sanchor[t];
    sel_boxes[b*NSEL + slot_base + t] = boxes_dec[(size_t)b*APIX + aa];
  }
}

// ---------------- IoU suppression bitmask: [B][3000 rows][256 u16] ------------------
// u16 at (row, w*64+lane) holds bits k=0..11 for slot j = k*256 + w*64 + lane.
__global__ __launch_bounds__(256) void k_mask(const float4* __restrict__ selb,
                                              unsigned* __restrict__ mask32){
  int b = blockIdx.x / 47, tile = blockIdx.x % 47;
  int row_base = tile*64;
  __shared__ float4 jb[NSEL];
  for (int i=threadIdx.x; i<NSEL; i+=256) jb[i] = selb[b*NSEL + i];
  __syncthreads();
  int t = threadIdx.x;
  int r0 = t & 15, w = (t>>4)&3, l0 = t>>6;
  float4 ib[4]; float ia[4]; int irow[4];
  #pragma unroll
  for (int ri=0; ri<4; ri++){
    int i = row_base + r0 + 16*ri; irow[ri] = i;
    float4 v = jb[(i < NSEL) ? i : 0]; ib[ri]=v;
    ia[ri] = fmaxf(v.z-v.x,0.f)*fmaxf(v.w-v.y,0.f);
  }
  unsigned acc[4][8];
  #pragma unroll
  for (int ri=0; ri<4; ri++)
    #pragma unroll
    for (int z=0; z<8; z++) acc[ri][z] = 0u;
  for (int k=0;k<12;k++){
    #pragma unroll
    for (int li=0; li<16; li++){
      int j = k*256 + w*64 + l0*16 + li;
      if (j >= NSEL) continue;
      float4 jv = jb[j];
      float ja = fmaxf(jv.z-jv.x,0.f)*fmaxf(jv.w-jv.y,0.f);
      #pragma unroll
      for (int ri=0; ri<4; ri++){
        float xx1 = fmaxf(ib[ri].x, jv.x), yy1 = fmaxf(ib[ri].y, jv.y);
        float xx2 = fminf(ib[ri].z, jv.z), yy2 = fminf(ib[ri].w, jv.w);
        float inter = fmaxf(xx2-xx1,0.f)*fmaxf(yy2-yy1,0.f);
        float denom = fmaxf(ia[ri] + ja - inter, 1e-9f);
        float iou = inter / denom;                 // exact ref formula, IEEE fp32 div
        if (iou > 0.5f) acc[ri][li>>1] |= (1u << (k + 16*(li&1)));
      }
    }
  }
  #pragma unroll
  for (int ri=0; ri<4; ri++){
    int i = irow[ri];
    if (i < NSEL){
      unsigned* dst = mask32 + ((size_t)(b*NSEL + i))*128 + (w*32 + l0*8);
      ((uint4*)dst)[0] = make_uint4(acc[ri][0],acc[ri][1],acc[ri][2],acc[ri][3]);
      ((uint4*)dst)[1] = make_uint4(acc[ri][4],acc[ri][5],acc[ri][6],acc[ri][7]);
    }
  }
}

// ---------------- greedy NMS per (image, class): register argmax + mask suppress ----
__global__ __launch_bounds__(256) void k_nms(const float* __restrict__ scores_t,
    const unsigned short* __restrict__ mask16,
    float* __restrict__ nms_s, unsigned* __restrict__ nms_slot){
  int c = blockIdx.x, b = blockIdx.y;
  const float* sc = scores_t + ((size_t)b*NCLS + c)*NSEL;
  int tid = threadIdx.x;
  unsigned long long key[12];
  #pragma unroll
  for (int k=0;k<12;k++){
    int slot = k*256 + tid;
    unsigned hi = 0x007FFFFFu;                       // sortable(-inf)
    if (slot < NSEL) hi = f2s(sc[slot]);
    key[k] = ((unsigned long long)hi << 32) | (unsigned)(3071 - slot);
  }
  __shared__ unsigned long long wred[4];
  float* outS = nms_s + ((size_t)b*NCLS + c)*TOPK;
  unsigned* outI = nms_slot + ((size_t)b*NCLS + c)*TOPK;
  int lane = tid & 63, wid = tid >> 6;
  for (int it=0; it<TOPK; it++){
    unsigned long long m = key[0];
    #pragma unroll
    for (int k=1;k<12;k++) m = key[k] > m ? key[k] : m;
    #pragma unroll
    for (int off=32; off; off>>=1){
      unsigned long long o = __shfl_xor(m, off, 64);
      m = o > m ? o : m;
    }
    if (lane == 0) wred[wid] = m;
    __syncthreads();
    unsigned long long m0 = wred[0], m1 = wred[1], m2 = wred[2], m3 = wred[3];
    unsigned long long ma = m0 > m1 ? m0 : m1;
    unsigned long long mb = m2 > m3 ? m2 : m3;
    unsigned long long mm = ma > mb ? ma : mb;
    unsigned slot = 3071u - (unsigned)(mm & 0xFFFFFFFFull);
    if (tid == 0){ outS[it] = s2f((unsigned)(mm>>32)); outI[it] = slot; }
    unsigned short mv = mask16[((size_t)(b*NSEL + slot))*256 + tid];
    #pragma unroll
    for (int k=0;k<12;k++){
      if ((mv >> k) & 1) key[k] = (0x007FFFFFull << 32) | (key[k] & 0xFFFFFFFFull);
    }
    __syncthreads();
  }
}

// ---------------- final top-100 via rank counting over 80 sorted lists --------------
__global__ __launch_bounds__(256) void k_out(const float* __restrict__ nms_s,
    const unsigned* __restrict__ nms_slot, const float4* __restrict__ selb,
    float* __restrict__ out){
  int b = blockIdx.x >> 5, chunk = blockIdx.x & 31;
  __shared__ float ls[8000];
  for (int i=threadIdx.x; i<8000; i+=256) ls[i] = nms_s[(size_t)b*8000 + i];
  __syncthreads();
  if (threadIdx.x >= 250) return;
  int e = chunk*250 + threadIdx.x;
  int c = e / 100, k = e - c*100;
  float s = ls[e];
  if (!(s > 0.3f)) return;
  int rank = k;                                    // own class: all k' < k rank above
  for (int c2=0; c2<NCLS; c2++){
    if (c2 == c) continue;
    const float* L = ls + c2*100;
    int lo=0, hi=100;
    while (lo < hi){ int mid=(lo+hi)>>1; if (L[mid] > s) lo=mid+1; else hi=mid; }
    if (c2 < c){                                   // ties in earlier class rank above (flat idx)
      int lo2=lo, hi2=100;
      while (lo2 < hi2){ int mid=(lo2+hi2)>>1; if (L[mid] >= s) lo2=mid+1; else hi2=mid; }
      rank += lo2;
    } else rank += lo;
    if (rank >= 100) return;
  }
  unsigned slot = nms_slot[(size_t)b*8000 + e];
  float4 bx = selb[b*NSEL + slot];
  float* o = out + ((size_t)b*100 + rank)*6;
  o[0]=bx.x; o[1]=bx.y; o[2]=bx.z; o[3]=bx.w; o[4]=s; o[5]=(float)c;
}

extern "C" void kernel_launch(void* const* d_in, const int* in_sizes, int n_in,
                              void* d_out, int out_size, void* d_ws, size_t ws_size,
                              hipStream_t stream){
  const float* cls0 = (const float*)d_in[0];
  const float* bp0  = (const float*)d_in[1];
  const float* cls1 = (const float*)d_in[2];
  const float* bp1  = (const float*)d_in[3];
  const float* cls2 = (const float*)d_in[4];
  const float* bp2  = (const float*)d_in[5];
  float* out = (float*)d_out;

  char* ws = (char*)d_ws;
  size_t off = 0;
  float*    scores_t  = (float*)(ws + off);              off += 7680000;   // [B][80][3000]
  unsigned* mask32    = (unsigned*)(ws + off);           off += 12288000;  // [B][3000][128]u32
  float4*   boxes_dec = (float4*)(ws + off);             off += 2752512;   // [B][21504]
  unsigned* keys      = (unsigned*)(ws + off);           off += 688128;    // [B][21504]
  unsigned* sel_idx   = (unsigned*)(ws + off);           off += 96000;     // [B][3000]
  float4*   sel_boxes = (float4*)(ws + off);             off += 384000;    // [B][3000] float4 = 384000 B (was 192000: overlap bug)
  float*    nms_s     = (float*)(ws + off);              off += 256000;    // [B][80][100]
  unsigned* nms_slot  = (unsigned*)(ws + off);           off += 256000;    // [B][80][100]
  unsigned long long* bnd = (unsigned long long*)(ws + off); off += 786432; // [24][4096]
  unsigned* thr       = (unsigned*)(ws + off);           off += 512;       // [24][4]
  size_t zoff = off;
  unsigned* hist      = (unsigned*)(ws + off);           off += 3145728;   // [24][32768]
  unsigned* sel_cnt   = (unsigned*)(ws + off);           off += 128;       // [24]
  unsigned* bnd_cnt   = (unsigned*)(ws + off);           off += 128;       // [24]

  hipMemsetAsync(ws + zoff, 0, 3145728 + 256, stream);
  hipMemsetAsync(d_out, 0, (size_t)out_size * sizeof(float), stream);

  k_decode<<<672, 256, 0, stream>>>(cls0, cls1, cls2, bp0, bp1, bp2, keys, boxes_dec, hist);
  k_thresh<<<24, 256, 0, stream>>>(hist, thr);
  k_select<<<672, 256, 0, stream>>>(keys, thr, sel_cnt, sel_idx, bnd, bnd_cnt);
  k_bnd<<<24, 256, 0, stream>>>(bnd, bnd_cnt, thr, sel_cnt, sel_idx);
  k_sortsel<<<24, 512, 0, stream>>>(keys, sel_idx);
  k_gather<<<376, 256, 0, stream>>>(cls0, cls1, cls2, sel_idx, boxes_dec, scores_t, sel_boxes);
  k_mask<<<376, 256, 0, stream>>>(sel_boxes, mask32);
  dim3 gnms(NCLS, BATCH);
  k_nms<<<gnms, 256, 0, stream>>>(scores_t, (const unsigned short*)mask32, nms_s, nms_slot);
  k_out<<<256, 256, 0, stream>>>(nms_s, nms_slot, sel_boxes, out);
}

// Round 4
// 528.013 us; speedup vs baseline: 1.2898x; 1.2898x over previous
//
#include <hip/hip_runtime.h>

#define BATCH 8
#define NCLS 80
#define APIX 21504   // anchors per image: 16384 + 4096 + 1024
#define AL0 16384
#define AL1 20480
#define NSEL 3000
#define TOPK 100
#define NBINS 32768
#define BNDCAP 4096

__device__ __forceinline__ unsigned f2s(float f){
  unsigned u = __float_as_uint(f);
  return (u & 0x80000000u) ? ~u : (u | 0x80000000u);
}
__device__ __forceinline__ float s2f(unsigned u){
  return (u & 0x80000000u) ? __uint_as_float(u ^ 0x80000000u) : __uint_as_float(~u);
}
__device__ __forceinline__ float sigd(float x){
  return (float)(1.0 / (1.0 + exp(-(double)x)));
}
__device__ __forceinline__ float expd(float x){
  return (float)exp((double)x);     // correctly-rounded fp32 exp (matches libm-class expf)
}

// ---------------- decode: maxlogit key + DFL box, histogram for radix-select --------
__global__ __launch_bounds__(256) void k_decode(
    const float* __restrict__ cls0, const float* __restrict__ cls1, const float* __restrict__ cls2,
    const float* __restrict__ bp0,  const float* __restrict__ bp1,  const float* __restrict__ bp2,
    unsigned* __restrict__ keys, float4* __restrict__ boxes, unsigned* __restrict__ hist){
  int gid = blockIdx.x*256 + threadIdx.x;
  if (gid >= BATCH*APIX) return;
  int b = gid / APIX, a = gid - b*APIX;
  const float *cls, *bp; int loc, W; float stride; int l;
  if (a < AL0){ l=0; loc=a;      W=128; stride=8.f;  cls=cls0 + (size_t)b*16384*80; bp=bp0 + (size_t)b*16384*32; }
  else if (a < AL1){ l=1; loc=a-AL0; W=64; stride=16.f; cls=cls1 + (size_t)b*4096*80; bp=bp1 + (size_t)b*4096*32; }
  else { l=2; loc=a-AL1; W=32; stride=32.f; cls=cls2 + (size_t)b*1024*80; bp=bp2 + (size_t)b*1024*32; }
  const float4* c4 = (const float4*)(cls + (size_t)loc*80);
  float m = -3.4e38f;
  #pragma unroll
  for (int i=0;i<20;i++){ float4 v = c4[i]; m = fmaxf(m, fmaxf(fmaxf(v.x,v.y), fmaxf(v.z,v.w))); }
  unsigned key = f2s(m);
  keys[gid] = key;
  atomicAdd(&hist[((b*3+l)<<15) + (key>>17)], 1u);

  const float4* p4 = (const float4*)(bp + (size_t)loc*32);
  float d[4];
  #pragma unroll
  for (int g=0; g<4; g++){
    float4 lo = p4[2*g], hi = p4[2*g+1];
    float mm = fmaxf(fmaxf(fmaxf(lo.x,lo.y),fmaxf(lo.z,lo.w)), fmaxf(fmaxf(hi.x,hi.y),fmaxf(hi.z,hi.w)));
    float e0=expd(lo.x-mm), e1=expd(lo.y-mm), e2=expd(lo.z-mm), e3=expd(lo.w-mm);
    float e4=expd(hi.x-mm), e5=expd(hi.y-mm), e6=expd(hi.z-mm), e7=expd(hi.w-mm);
    float s = e0+e1+e2+e3+e4+e5+e6+e7;
    // ref: softmax (per-element divide) then dot with [0..7]
    float dot = (e1/s) + 2.f*(e2/s) + 3.f*(e3/s) + 4.f*(e4/s) + 5.f*(e5/s) + 6.f*(e6/s) + 7.f*(e7/s);
    d[g] = dot * stride;   // stride is a power of two: exact scaling, matches ref
  }
  float py = ((float)(loc / W) + 0.5f) * stride;
  float px = ((float)(loc % W) + 0.5f) * stride;
  float y1v = fminf(fmaxf(py - d[0], 0.f), 1024.f);
  float x1v = fminf(fmaxf(px - d[1], 0.f), 1024.f);
  float y2v = fminf(fmaxf(py + d[2], 0.f), 1024.f);
  float x2v = fminf(fmaxf(px + d[3], 0.f), 1024.f);
  boxes[gid] = make_float4(x1v, y1v, x2v, y2v);
}

// ---------------- find top-1000 threshold bin per (image, level) --------------------
__global__ __launch_bounds__(256) void k_thresh(const unsigned* __restrict__ hist,
                                                unsigned* __restrict__ thr){
  int bl = blockIdx.x;
  const unsigned* h = hist + ((size_t)bl << 15);
  __shared__ unsigned part[256];
  int t = threadIdx.x;
  unsigned sum = 0; int base = t*128;
  for (int i=0;i<128;i++) sum += h[base+i];
  part[t] = sum;
  __syncthreads();
  for (int off=1; off<256; off<<=1){              // inclusive suffix sum over chunks
    unsigned v = part[t];
    unsigned add = (t+off < 256) ? part[t+off] : 0u;
    __syncthreads();
    part[t] = v + add;
    __syncthreads();
  }
  unsigned sfx = part[t];
  unsigned nxt = (t==255) ? 0u : part[t+1];
  if (sfx >= 1000u && nxt < 1000u){               // crossing chunk: exactly one thread
    unsigned c = nxt;
    for (int u=127; u>=0; u--){
      unsigned hv = h[base+u];
      c += hv;
      if (c >= 1000u){
        thr[bl*4+0] = (unsigned)(base+u);          // T
        thr[bl*4+1] = c - hv;                      // count strictly above T
        thr[bl*4+2] = 1000u - (c - hv);            // r from boundary bin
        break;
      }
    }
  }
}

// ---------------- compaction: wave-aggregated atomics (fix: 180us same-address contention)
__global__ __launch_bounds__(256) void k_select(const unsigned* __restrict__ keys,
    const unsigned* __restrict__ thr, unsigned* __restrict__ sel_cnt,
    unsigned* __restrict__ sel_idx, unsigned long long* __restrict__ bnd,
    unsigned* __restrict__ bnd_cnt){
  int gid = blockIdx.x*256 + threadIdx.x;          // grid exact: 672*256 == 8*21504
  int b = gid / APIX, a = gid - b*APIX;
  int l = (a < AL0) ? 0 : (a < AL1 ? 1 : 2);       // wave-uniform (level edges % 64 == 0)
  unsigned key = keys[gid];
  int bl = b*3 + l;
  unsigned T = thr[bl*4];
  unsigned bin = key >> 17;
  unsigned lane = threadIdx.x & 63;
  unsigned long long lt = (lane == 0) ? 0ull : (~0ull >> (64u - lane));
  bool is_sel = (bin > T), is_bnd = (bin == T);
  unsigned long long msel = __ballot(is_sel);
  unsigned long long mbnd = __ballot(is_bnd);
  unsigned sbase = 0, bbase = 0;
  if (lane == 0){
    if (msel) sbase = atomicAdd(&sel_cnt[bl], (unsigned)__popcll(msel));
    if (mbnd) bbase = atomicAdd(&bnd_cnt[bl], (unsigned)__popcll(mbnd));
  }
  sbase = __shfl(sbase, 0, 64);
  bbase = __shfl(bbase, 0, 64);
  if (is_sel){
    sel_idx[b*NSEL + l*1000 + sbase + (unsigned)__popcll(msel & lt)] = (unsigned)a;
  }
  if (is_bnd){
    unsigned q = bbase + (unsigned)__popcll(mbnd & lt);
    if (q < BNDCAP) bnd[(size_t)bl*BNDCAP + q] = ((unsigned long long)key << 32) | (0xFFFFFFFFu - (unsigned)a);
  }
}

// ---------------- exact rank within boundary bin ------------------------------------
__global__ __launch_bounds__(256) void k_bnd(const unsigned long long* __restrict__ bnd,
    const unsigned* __restrict__ bnd_cnt, const unsigned* __restrict__ thr,
    unsigned* __restrict__ sel_cnt, unsigned* __restrict__ sel_idx){
  int bl = blockIdx.x; int b = bl/3, l = bl%3;
  __shared__ unsigned long long sb[BNDCAP];
  unsigned Q = bnd_cnt[bl]; if (Q > (unsigned)BNDCAP) Q = BNDCAP;
  unsigned r = thr[bl*4 + 2];
  for (unsigned i=threadIdx.x; i<Q; i+=256) sb[i] = bnd[(size_t)bl*BNDCAP + i];
  __syncthreads();
  for (unsigned i=threadIdx.x; i<Q; i+=256){
    unsigned long long me = sb[i];
    unsigned rank = 0;
    for (unsigned j=0; j<Q; j++) rank += (sb[j] > me) ? 1u : 0u;
    if (rank < r){
      unsigned p = atomicAdd(&sel_cnt[bl], 1u);
      sel_idx[b*NSEL + l*1000 + p] = 0xFFFFFFFFu - (unsigned)(me & 0xFFFFFFFFull);
    }
  }
}

// ---------------- sort each level's 1000 by (maxlogit desc, idx asc) — match top_k order
__global__ __launch_bounds__(512) void k_sortsel(const unsigned* __restrict__ keys,
                                                 unsigned* __restrict__ sel_idx){
  int bl = blockIdx.x; int b = bl/3, l = bl%3;
  __shared__ unsigned long long s[1024];
  unsigned* base = sel_idx + b*NSEL + l*1000;
  int t = threadIdx.x;
  for (int i=t; i<1024; i+=512){
    unsigned long long v = 0ull;                  // padding: strictly smallest
    if (i < 1000){
      unsigned a = base[i];
      v = ((unsigned long long)keys[(size_t)b*APIX + a] << 32) | (0xFFFFFFFFu - a);
    }
    s[i] = v;
  }
  __syncthreads();
  for (int k=2; k<=1024; k<<=1){
    for (int j=k>>1; j>0; j>>=1){
      for (int i=t; i<1024; i+=512){
        int ixj = i ^ j;
        if (ixj > i){
          bool up = ((i & k) == 0);
          unsigned long long x = s[i], y = s[ixj];
          bool sw = up ? (x < y) : (x > y);       // descending sort
          if (sw){ s[i] = y; s[ixj] = x; }
        }
      }
      __syncthreads();
    }
  }
  for (int i=t; i<1000; i+=512) base[i] = 0xFFFFFFFFu - (unsigned)(s[i] & 0xFFFFFFFFull);
}

// ---------------- gather per-class scores (transposed) + selected boxes -------------
__global__ __launch_bounds__(256) void k_gather(
    const float* __restrict__ cls0, const float* __restrict__ cls1, const float* __restrict__ cls2,
    const unsigned* __restrict__ sel_idx, const float4* __restrict__ boxes_dec,
    float* __restrict__ scores_t, float4* __restrict__ sel_boxes){
  int b = blockIdx.x / 47, tile = blockIdx.x % 47;
  int slot_base = tile*64;
  __shared__ float tilebuf[64][84];
  __shared__ unsigned sanchor[64];
  int t = threadIdx.x, sl = t & 63, cg = t >> 6;
  int slot = slot_base + sl;
  bool valid = slot < NSEL;
  if (t < 64){
    int s2 = slot_base + t;
    sanchor[t] = (s2 < NSEL) ? sel_idx[b*NSEL + s2] : 0u;
  }
  __syncthreads();
  unsigned a = sanchor[sl];
  const float* crow;
  if (a < AL0)      crow = cls0 + ((size_t)b*16384 + a)*80;
  else if (a < AL1) crow = cls1 + ((size_t)b*4096 + (a-AL0))*80;
  else              crow = cls2 + ((size_t)b*1024 + (a-AL1))*80;
  const float4* c4 = (const float4*)crow + cg*5;
  float4 v0=c4[0], v1=c4[1], v2=c4[2], v3=c4[3], v4=c4[4];
  float4* drow = (float4*)&tilebuf[sl][cg*20];
  drow[0]=v0; drow[1]=v1; drow[2]=v2; drow[3]=v3; drow[4]=v4;
  __syncthreads();
  #pragma unroll
  for (int it=0; it<20; it++){
    int cc = it*4 + cg;
    if (valid) scores_t[((size_t)b*NCLS + cc)*NSEL + slot] = sigd(tilebuf[sl][cc]);
  }
  if (t < 64 && slot_base + t < NSEL){
    unsigned aa = sanchor[t];
    sel_boxes[b*NSEL + slot_base + t] = boxes_dec[(size_t)b*APIX + aa];
  }
}

// ---------------- IoU suppression bitmask: [B][3000 rows][256 u16] ------------------
// u16 at (row, w*64+lane) holds bits k=0..11 for slot j = k*256 + w*64 + lane.
__global__ __launch_bounds__(256) void k_mask(const float4* __restrict__ selb,
                                              unsigned* __restrict__ mask32){
  int b = blockIdx.x / 47, tile = blockIdx.x % 47;
  int row_base = tile*64;
  __shared__ float4 jb[NSEL];
  for (int i=threadIdx.x; i<NSEL; i+=256) jb[i] = selb[b*NSEL + i];
  __syncthreads();
  int t = threadIdx.x;
  int r0 = t & 15, w = (t>>4)&3, l0 = t>>6;
  float4 ib[4]; float ia[4]; int irow[4];
  #pragma unroll
  for (int ri=0; ri<4; ri++){
    int i = row_base + r0 + 16*ri; irow[ri] = i;
    float4 v = jb[(i < NSEL) ? i : 0]; ib[ri]=v;
    ia[ri] = fmaxf(v.z-v.x,0.f)*fmaxf(v.w-v.y,0.f);
  }
  unsigned acc[4][8];
  #pragma unroll
  for (int ri=0; ri<4; ri++)
    #pragma unroll
    for (int z=0; z<8; z++) acc[ri][z] = 0u;
  for (int k=0;k<12;k++){
    #pragma unroll
    for (int li=0; li<16; li++){
      int j = k*256 + w*64 + l0*16 + li;
      if (j >= NSEL) continue;
      float4 jv = jb[j];
      float ja = fmaxf(jv.z-jv.x,0.f)*fmaxf(jv.w-jv.y,0.f);
      #pragma unroll
      for (int ri=0; ri<4; ri++){
        float xx1 = fmaxf(ib[ri].x, jv.x), yy1 = fmaxf(ib[ri].y, jv.y);
        float xx2 = fminf(ib[ri].z, jv.z), yy2 = fminf(ib[ri].w, jv.w);
        float inter = fmaxf(xx2-xx1,0.f)*fmaxf(yy2-yy1,0.f);
        float denom = fmaxf(ia[ri] + ja - inter, 1e-9f);
        float iou = inter / denom;                 // exact ref formula, IEEE fp32 div
        if (iou > 0.5f) acc[ri][li>>1] |= (1u << (k + 16*(li&1)));
      }
    }
  }
  #pragma unroll
  for (int ri=0; ri<4; ri++){
    int i = irow[ri];
    if (i < NSEL){
      unsigned* dst = mask32 + ((size_t)(b*NSEL + i))*128 + (w*32 + l0*8);
      ((uint4*)dst)[0] = make_uint4(acc[ri][0],acc[ri][1],acc[ri][2],acc[ri][3]);
      ((uint4*)dst)[1] = make_uint4(acc[ri][4],acc[ri][5],acc[ri][6],acc[ri][7]);
    }
  }
}

// ---------------- greedy NMS per (image, class): register argmax + mask suppress ----
__global__ __launch_bounds__(256) void k_nms(const float* __restrict__ scores_t,
    const unsigned short* __restrict__ mask16,
    float* __restrict__ nms_s, unsigned* __restrict__ nms_slot){
  int c = blockIdx.x, b = blockIdx.y;
  const float* sc = scores_t + ((size_t)b*NCLS + c)*NSEL;
  int tid = threadIdx.x;
  unsigned long long key[12];
  #pragma unroll
  for (int k=0;k<12;k++){
    int slot = k*256 + tid;
    unsigned hi = 0x007FFFFFu;                       // sortable(-inf)
    if (slot < NSEL) hi = f2s(sc[slot]);
    key[k] = ((unsigned long long)hi << 32) | (unsigned)(3071 - slot);
  }
  __shared__ unsigned long long wred[4];
  float* outS = nms_s + ((size_t)b*NCLS + c)*TOPK;
  unsigned* outI = nms_slot + ((size_t)b*NCLS + c)*TOPK;
  int lane = tid & 63, wid = tid >> 6;
  for (int it=0; it<TOPK; it++){
    unsigned long long m = key[0];
    #pragma unroll
    for (int k=1;k<12;k++) m = key[k] > m ? key[k] : m;
    #pragma unroll
    for (int off=32; off; off>>=1){
      unsigned long long o = __shfl_xor(m, off, 64);
      m = o > m ? o : m;
    }
    if (lane == 0) wred[wid] = m;
    __syncthreads();
    unsigned long long m0 = wred[0], m1 = wred[1], m2 = wred[2], m3 = wred[3];
    unsigned long long ma = m0 > m1 ? m0 : m1;
    unsigned long long mb = m2 > m3 ? m2 : m3;
    unsigned long long mm = ma > mb ? ma : mb;
    unsigned slot = 3071u - (unsigned)(mm & 0xFFFFFFFFull);
    if (tid == 0){ outS[it] = s2f((unsigned)(mm>>32)); outI[it] = slot; }
    unsigned short mv = mask16[((size_t)(b*NSEL + slot))*256 + tid];
    #pragma unroll
    for (int k=0;k<12;k++){
      if ((mv >> k) & 1) key[k] = (0x007FFFFFull << 32) | (key[k] & 0xFFFFFFFFull);
    }
    __syncthreads();
  }
}

// ---------------- final top-100 via rank counting over 80 sorted lists --------------
__global__ __launch_bounds__(256) void k_out(const float* __restrict__ nms_s,
    const unsigned* __restrict__ nms_slot, const float4* __restrict__ selb,
    float* __restrict__ out){
  int b = blockIdx.x >> 5, chunk = blockIdx.x & 31;
  __shared__ float ls[8000];
  for (int i=threadIdx.x; i<8000; i+=256) ls[i] = nms_s[(size_t)b*8000 + i];
  __syncthreads();
  if (threadIdx.x >= 250) return;
  int e = chunk*250 + threadIdx.x;
  int c = e / 100, k = e - c*100;
  float s = ls[e];
  if (!(s > 0.3f)) return;
  int rank = k;                                    // own class: all k' < k rank above
  for (int c2=0; c2<NCLS; c2++){
    if (c2 == c) continue;
    const float* L = ls + c2*100;
    int lo=0, hi=100;
    while (lo < hi){ int mid=(lo+hi)>>1; if (L[mid] > s) lo=mid+1; else hi=mid; }
    if (c2 < c){                                   // ties in earlier class rank above (flat idx)
      int lo2=lo, hi2=100;
      while (lo2 < hi2){ int mid=(lo2+hi2)>>1; if (L[mid] >= s) lo2=mid+1; else hi2=mid; }
      rank += lo2;
    } else rank += lo;
    if (rank >= 100) return;
  }
  unsigned slot = nms_slot[(size_t)b*8000 + e];
  float4 bx = selb[b*NSEL + slot];
  float* o = out + ((size_t)b*100 + rank)*6;
  o[0]=bx.x; o[1]=bx.y; o[2]=bx.z; o[3]=bx.w; o[4]=s; o[5]=(float)c;
}

extern "C" void kernel_launch(void* const* d_in, const int* in_sizes, int n_in,
                              void* d_out, int out_size, void* d_ws, size_t ws_size,
                              hipStream_t stream){
  const float* cls0 = (const float*)d_in[0];
  const float* bp0  = (const float*)d_in[1];
  const float* cls1 = (const float*)d_in[2];
  const float* bp1  = (const float*)d_in[3];
  const float* cls2 = (const float*)d_in[4];
  const float* bp2  = (const float*)d_in[5];
  float* out = (float*)d_out;

  char* ws = (char*)d_ws;
  size_t off = 0;
  float*    scores_t  = (float*)(ws + off);              off += 7680000;   // [B][80][3000]
  unsigned* mask32    = (unsigned*)(ws + off);           off += 12288000;  // [B][3000][128]u32
  float4*   boxes_dec = (float4*)(ws + off);             off += 2752512;   // [B][21504]
  unsigned* keys      = (unsigned*)(ws + off);           off += 688128;    // [B][21504]
  unsigned* sel_idx   = (unsigned*)(ws + off);           off += 96000;     // [B][3000]
  float4*   sel_boxes = (float4*)(ws + off);             off += 384000;    // [B][3000] float4
  float*    nms_s     = (float*)(ws + off);              off += 256000;    // [B][80][100]
  unsigned* nms_slot  = (unsigned*)(ws + off);           off += 256000;    // [B][80][100]
  unsigned long long* bnd = (unsigned long long*)(ws + off); off += 786432; // [24][4096]
  unsigned* thr       = (unsigned*)(ws + off);           off += 512;       // [24][4]
  size_t zoff = off;
  unsigned* hist      = (unsigned*)(ws + off);           off += 3145728;   // [24][32768]
  unsigned* sel_cnt   = (unsigned*)(ws + off);           off += 128;       // [24]
  unsigned* bnd_cnt   = (unsigned*)(ws + off);           off += 128;       // [24]

  hipMemsetAsync(ws + zoff, 0, 3145728 + 256, stream);
  hipMemsetAsync(d_out, 0, (size_t)out_size * sizeof(float), stream);

  k_decode<<<672, 256, 0, stream>>>(cls0, cls1, cls2, bp0, bp1, bp2, keys, boxes_dec, hist);
  k_thresh<<<24, 256, 0, stream>>>(hist, thr);
  k_select<<<672, 256, 0, stream>>>(keys, thr, sel_cnt, sel_idx, bnd, bnd_cnt);
  k_bnd<<<24, 256, 0, stream>>>(bnd, bnd_cnt, thr, sel_cnt, sel_idx);
  k_sortsel<<<24, 512, 0, stream>>>(keys, sel_idx);
  k_gather<<<376, 256, 0, stream>>>(cls0, cls1, cls2, sel_idx, boxes_dec, scores_t, sel_boxes);
  k_mask<<<376, 256, 0, stream>>>(sel_boxes, mask32);
  dim3 gnms(NCLS, BATCH);
  k_nms<<<gnms, 256, 0, stream>>>(scores_t, (const unsigned short*)mask32, nms_s, nms_slot);
  k_out<<<256, 256, 0, stream>>>(nms_s, nms_slot, sel_boxes, out);
}